// Round 1
// baseline (1481.320 us; speedup 1.0000x reference)
//
#include <hip/hip_runtime.h>
#include <hip/hip_bf16.h>
#include <cstdint>
#include <cstddef>

// ---------------- wave helpers (wave64) ----------------
__device__ __forceinline__ float wave_max_f(float v){
  #pragma unroll
  for (int m = 32; m; m >>= 1) v = fmaxf(v, __shfl_xor(v, m));
  return v;
}
__device__ __forceinline__ float wave_sum_f(float v){
  #pragma unroll
  for (int m = 32; m; m >>= 1) v += __shfl_xor(v, m);
  return v;
}

// ---------------- _sample_early: gather + normalize ----------------
// out row r = b*64+p : out[r,c] = feat[b,c,pid[p]] / max(||.||, 1e-7)
template<int C, int LOGHW>
__global__ __launch_bounds__(64)
void sample_kernel(const float* __restrict__ feat, const int* __restrict__ pid,
                   float* __restrict__ out){
  const int r = blockIdx.x;          // 0..127
  const int b = r >> 6, p = r & 63;
  const int lane = threadIdx.x;      // 0..63
  const int l = pid[p];
  const float* fb = feat + (((size_t)b * C) << LOGHW);
  constexpr int V = C / 64;
  float v[V];
  float sq = 0.f;
  #pragma unroll
  for (int i = 0; i < V; ++i){
    const int c = lane + 64 * i;
    v[i] = fb[(((size_t)c) << LOGHW) + l];
    sq += v[i] * v[i];
  }
  sq = wave_sum_f(sq);
  const float nrm = fmaxf(sqrtf(sq), 1e-7f);
  #pragma unroll
  for (int i = 0; i < V; ++i)
    out[(size_t)r * C + lane + 64 * i] = v[i] / nrm;
}

// ---------------- qs_attn constants ----------------
#define C3   256
#define HW3  4096
#define W3   64
#define NP   64

// ---------------- entropy of local attention ----------------
// One wave per position l; lane = k2 (0..48). Scrambled mapping:
// f = k2*256 + c2 ; c = f/49 ; k = f%49 ; window offset (k/7-3, k%7-3)
__global__ __launch_bounds__(256)
void entropy_kernel(const float* __restrict__ feat3, float* __restrict__ ent_out){
  __shared__ float fr[4][C3];
  const int blk = blockIdx.x;          // 0..2047
  const int b   = blk >> 10;
  const int l0  = (blk & 1023) * 4;
  const int tid = threadIdx.x;

  { // stage fr for 4 consecutive positions; thread tid owns channel tid
    const float4 v = *reinterpret_cast<const float4*>(
        feat3 + (((size_t)(b * C3 + tid)) << 12) + l0);
    fr[0][tid] = v.x; fr[1][tid] = v.y; fr[2][tid] = v.z; fr[3][tid] = v.w;
  }
  __syncthreads();

  const int wid = tid >> 6, lane = tid & 63;
  const int l = l0 + wid;
  const int h = l >> 6, w = l & 63;
  const float* fb = feat3 + ((size_t)b * C3 << 12);

  float dot = -INFINITY;
  if (lane < 49){
    float acc = 0.f;
    int f  = lane * 256;
    int c  = f / 49;
    int k  = f % 49;
    int ki = k / 7, kj = k % 7;
    for (int c2 = 0; c2 < 256; ++c2){
      const int hh = h + ki - 3, ww = w + kj - 3;
      float wv = 0.f;
      if ((unsigned)hh < 64u && (unsigned)ww < 64u)
        wv = fb[((size_t)c << 12) + (hh << 6) + ww];
      acc += wv * fr[wid][c2];
      ++kj;
      if (kj == 7){ kj = 0; ++ki; if (ki == 7){ ki = 0; ++c; } }
    }
    dot = acc;
  }
  // softmax + entropy across lanes 0..48
  const float m = wave_max_f(dot);
  const float e = (lane < 49) ? expf(dot - m) : 0.f;
  const float s = wave_sum_f(e);
  const float t = (lane < 49) ? e * (dot - m) : 0.f;
  const float ts = wave_sum_f(t);
  const float ent = logf(s) - ts / s;
  if (lane == 0) ent_out[b * HW3 + l] = ent;
}

// ---------------- select 64 lowest-entropy indices (stable) ----------------
__global__ __launch_bounds__(1024)
void select_kernel(const float* __restrict__ ent, int* __restrict__ idx){
  __shared__ float el[HW3];
  __shared__ float be[16];
  __shared__ int   bi[16];
  const int b = blockIdx.x, t = threadIdx.x;
  #pragma unroll
  for (int i = 0; i < 4; ++i) el[t + 1024 * i] = ent[b * HW3 + t + 1024 * i];
  __syncthreads();
  const int lane = t & 63, wid = t >> 6;
  for (int it = 0; it < NP; ++it){
    float bestE = INFINITY; int bestI = 0x7fffffff;
    #pragma unroll
    for (int i = 0; i < 4; ++i){
      const int j = t + 1024 * i;
      const float e = el[j];
      if (e < bestE || (e == bestE && j < bestI)){ bestE = e; bestI = j; }
    }
    #pragma unroll
    for (int m = 32; m; m >>= 1){
      const float oe = __shfl_xor(bestE, m);
      const int   oi = __shfl_xor(bestI, m);
      if (oe < bestE || (oe == bestE && oi < bestI)){ bestE = oe; bestI = oi; }
    }
    if (lane == 0){ be[wid] = bestE; bi[wid] = bestI; }
    __syncthreads();
    if (t == 0){
      float e0 = be[0]; int i0 = bi[0];
      for (int wv = 1; wv < 16; ++wv)
        if (be[wv] < e0 || (be[wv] == e0 && bi[wv] < i0)){ e0 = be[wv]; i0 = bi[wv]; }
      idx[b * NP + it] = i0;
      el[i0] = INFINITY;
    }
    __syncthreads();
  }
}

// ---------------- global attention rows + normalize ----------------
// one block (256 thr) per (b,p)
__global__ __launch_bounds__(256)
void gattn_kernel(const float* __restrict__ feat3, const int* __restrict__ idx,
                  float* __restrict__ out3){
  __shared__ float q[C3];
  __shared__ float dl[HW3];
  __shared__ float red[4];
  __shared__ float oc[C3];
  const int blk = blockIdx.x;     // 0..127
  const int b = blk >> 6, p = blk & 63;
  const int t = threadIdx.x, lane = t & 63, wid = t >> 6;
  const float* fb = feat3 + ((size_t)b * C3 << 12);
  const int pidx = idx[b * NP + p];

  q[t] = fb[((size_t)t << 12) + pidx];
  __syncthreads();

  float acc[16];
  #pragma unroll
  for (int i = 0; i < 16; ++i) acc[i] = 0.f;
  for (int c = 0; c < C3; ++c){
    const float qc = q[c];
    const float* row = fb + ((size_t)c << 12);
    #pragma unroll
    for (int i = 0; i < 16; ++i) acc[i] += row[(i << 8) + t] * qc;
  }
  // softmax over 4096
  float lm = -INFINITY;
  #pragma unroll
  for (int i = 0; i < 16; ++i) lm = fmaxf(lm, acc[i]);
  lm = wave_max_f(lm);
  if (lane == 0) red[wid] = lm;
  __syncthreads();
  const float m = fmaxf(fmaxf(red[0], red[1]), fmaxf(red[2], red[3]));
  float ls = 0.f;
  #pragma unroll
  for (int i = 0; i < 16; ++i){ acc[i] = expf(acc[i] - m); ls += acc[i]; }
  ls = wave_sum_f(ls);
  __syncthreads();
  if (lane == 0) red[wid] = ls;
  __syncthreads();
  const float s = red[0] + red[1] + red[2] + red[3];
  const float inv = 1.f / s;
  #pragma unroll
  for (int i = 0; i < 16; ++i) dl[(i << 8) + t] = acc[i] * inv;
  __syncthreads();
  // out[c] = sum_l p[l] * fr[l,c] ; wave wid owns channels [64*wid, 64*wid+63]
  for (int cc = 0; cc < 64; ++cc){
    const int c = (wid << 6) + cc;
    const float* row = fb + ((size_t)c << 12);
    float partial = 0.f;
    #pragma unroll
    for (int i = 0; i < 64; ++i)
      partial += dl[(i << 6) + lane] * row[(i << 6) + lane];
    partial = wave_sum_f(partial);
    if (lane == 0) oc[c] = partial;
  }
  __syncthreads();
  // normalize row of 256
  const float v = oc[t];
  float sq = v * v;
  sq = wave_sum_f(sq);
  __syncthreads();          // red reuse safe: all prior reads done
  if (lane == 0) red[wid] = sq;
  __syncthreads();
  const float nrm = fmaxf(sqrtf(red[0] + red[1] + red[2] + red[3]), 1e-7f);
  out3[(size_t)((b << 6) + p) * C3 + t] = v / nrm;
}

// ---------------- launch ----------------
extern "C" void kernel_launch(void* const* d_in, const int* in_sizes, int n_in,
                              void* d_out, int out_size, void* d_ws, size_t ws_size,
                              hipStream_t stream){
  const float* feat0 = (const float*)d_in[0];   // [2,64,256,256]
  const float* feat1 = (const float*)d_in[1];   // [2,128,128,128]
  const float* feat2 = (const float*)d_in[2];   // [2,256,64,64]
  const float* feat3 = (const float*)d_in[3];   // [2,256,64,64]
  const int*   pid0  = (const int*)d_in[4];
  const int*   pid1  = (const int*)d_in[5];
  const int*   pid2  = (const int*)d_in[6];
  // d_in[7] = num_patches (fixed 64)

  float* out  = (float*)d_out;
  float* out0 = out;                 // 128*64
  float* out1 = out + 8192;          // 128*128
  float* out2 = out + 24576;         // 128*256
  float* out3 = out + 57344;         // 128*256

  float* ent_ws = (float*)d_ws;                  // 2*4096 floats
  int*   idx_ws = (int*)(ent_ws + 2 * HW3);      // 2*64 ints

  sample_kernel<64, 16><<<128, 64, 0, stream>>>(feat0, pid0, out0);
  sample_kernel<128, 14><<<128, 64, 0, stream>>>(feat1, pid1, out1);
  sample_kernel<256, 12><<<128, 64, 0, stream>>>(feat2, pid2, out2);

  entropy_kernel<<<2048, 256, 0, stream>>>(feat3, ent_ws);
  select_kernel<<<2, 1024, 0, stream>>>(ent_ws, idx_ws);
  gattn_kernel<<<128, 256, 0, stream>>>(feat3, idx_ws, out3);
}

// Round 2
// 278.415 us; speedup vs baseline: 5.3205x; 5.3205x over previous
//
#include <hip/hip_runtime.h>
#include <hip/hip_bf16.h>
#include <cstdint>
#include <cstddef>

// ---------------- wave helpers (wave64) ----------------
__device__ __forceinline__ float wave_max_f(float v){
  #pragma unroll
  for (int m = 32; m; m >>= 1) v = fmaxf(v, __shfl_xor(v, m));
  return v;
}
__device__ __forceinline__ float wave_sum_f(float v){
  #pragma unroll
  for (int m = 32; m; m >>= 1) v += __shfl_xor(v, m);
  return v;
}

// ---------------- _sample_early: gather + normalize ----------------
template<int C, int LOGHW>
__global__ __launch_bounds__(64)
void sample_kernel(const float* __restrict__ feat, const int* __restrict__ pid,
                   float* __restrict__ out){
  const int r = blockIdx.x;          // 0..127
  const int b = r >> 6, p = r & 63;
  const int lane = threadIdx.x;      // 0..63
  const int l = pid[p];
  const float* fb = feat + (((size_t)b * C) << LOGHW);
  constexpr int V = C / 64;
  float v[V];
  float sq = 0.f;
  #pragma unroll
  for (int i = 0; i < V; ++i){
    const int c = lane + 64 * i;
    v[i] = fb[(((size_t)c) << LOGHW) + l];
    sq += v[i] * v[i];
  }
  sq = wave_sum_f(sq);
  const float nrm = fmaxf(sqrtf(sq), 1e-7f);
  #pragma unroll
  for (int i = 0; i < V; ++i)
    out[(size_t)r * C + lane + 64 * i] = v[i] / nrm;
}

// ---------------- qs_attn constants ----------------
#define C3   256
#define HW3  4096
#define NP   64

// ---------------- local dots (scrambled faithful mapping) ----------------
// grid = 2*64*13 ; block 256. Wave wid handles k2 = kg*4+wid (k2<49).
// lane = w (coalesced in w for both the window load and the fr load).
__global__ __launch_bounds__(256)
void ldots_kernel(const float* __restrict__ feat3, float* __restrict__ dotsl){
  const int blk = blockIdx.x;
  const int kg = blk % 13;
  const int bh = blk / 13;
  const int b = bh >> 6, h = bh & 63;
  const int tid = threadIdx.x, wid = tid >> 6, lane = tid & 63;
  const int k2 = kg * 4 + wid;
  if (k2 >= 49) return;
  const float* fb = feat3 + ((size_t)b << 20);
  const int w = lane;
  const int f0 = k2 << 8;
  int c  = f0 / 49;
  int k  = f0 % 49;
  int ki = k / 7, kj = k % 7;
  float acc = 0.f;
  for (int c2 = 0; c2 < 256; ++c2){
    const int hh = h + ki - 3;
    const int ww = w + kj - 3;
    float wv = 0.f;
    if ((unsigned)hh < 64u && (unsigned)ww < 64u)
      wv = fb[((size_t)c << 12) + (hh << 6) + ww];
    acc += wv * fb[((size_t)c2 << 12) + (h << 6) + w];
    ++kj;
    if (kj == 7){ kj = 0; ++ki; if (ki == 7){ ki = 0; ++c; } }
  }
  dotsl[(((size_t)(b * 49 + k2)) << 12) + (h << 6) + w] = acc;
}

// ---------------- local entropy (softmax over 49, k-major layout) ----------
__global__ __launch_bounds__(256)
void lent_kernel(const float* __restrict__ dotsl, float* __restrict__ ent){
  const int blk = blockIdx.x;       // 32
  const int b = blk >> 4;
  const int l = ((blk & 15) << 8) + threadIdx.x;
  const float* dl = dotsl + (((size_t)b * 49) << 12);
  float m = -INFINITY;
  #pragma unroll
  for (int k = 0; k < 49; ++k) m = fmaxf(m, dl[((size_t)k << 12) + l]);
  float s = 0.f, ts = 0.f;
  #pragma unroll
  for (int k = 0; k < 49; ++k){
    const float d = dl[((size_t)k << 12) + l] - m;
    const float e = expf(d);
    s += e; ts += e * d;
  }
  ent[b * HW3 + l] = logf(s) - ts / s;
}

// ---------------- select 64 lowest-entropy indices (stable) ----------------
__global__ __launch_bounds__(1024)
void select_kernel(const float* __restrict__ ent, int* __restrict__ idx){
  __shared__ float el[HW3];
  __shared__ float be[16];
  __shared__ int   bi[16];
  const int b = blockIdx.x, t = threadIdx.x;
  #pragma unroll
  for (int i = 0; i < 4; ++i) el[t + 1024 * i] = ent[b * HW3 + t + 1024 * i];
  __syncthreads();
  const int lane = t & 63, wid = t >> 6;
  for (int it = 0; it < NP; ++it){
    float bestE = INFINITY; int bestI = 0x7fffffff;
    #pragma unroll
    for (int i = 0; i < 4; ++i){
      const int j = t + 1024 * i;
      const float e = el[j];
      if (e < bestE || (e == bestE && j < bestI)){ bestE = e; bestI = j; }
    }
    #pragma unroll
    for (int m = 32; m; m >>= 1){
      const float oe = __shfl_xor(bestE, m);
      const int   oi = __shfl_xor(bestI, m);
      if (oe < bestE || (oe == bestE && oi < bestI)){ bestE = oe; bestI = oi; }
    }
    if (lane == 0){ be[wid] = bestE; bi[wid] = bestI; }
    __syncthreads();
    if (t == 0){
      float e0 = be[0]; int i0 = bi[0];
      for (int wv = 1; wv < 16; ++wv)
        if (be[wv] < e0 || (be[wv] == e0 && bi[wv] < i0)){ e0 = be[wv]; i0 = bi[wv]; }
      idx[b * NP + it] = i0;
      el[i0] = INFINITY;
    }
    __syncthreads();
  }
}

// ---------------- global dots: grid (b,p) x 16 l-chunks -------------------
__global__ __launch_bounds__(256)
void gdots_kernel(const float* __restrict__ feat3, const int* __restrict__ idx,
                  float* __restrict__ dg, float* __restrict__ bmax){
  __shared__ float q_sh[C3];
  __shared__ float red[4];
  const int blk = blockIdx.x;       // 2048
  const int bp = blk >> 4, lc = blk & 15;
  const int b = bp >> 6;
  const int t = threadIdx.x, lane = t & 63, wid = t >> 6;
  const float* fb = feat3 + ((size_t)b << 20);
  const int pidx = idx[bp];
  q_sh[t] = fb[((size_t)t << 12) + pidx];
  __syncthreads();
  const int l = (lc << 8) + t;
  float acc = 0.f;
  #pragma unroll 8
  for (int c = 0; c < C3; ++c) acc += fb[((size_t)c << 12) + l] * q_sh[c];
  dg[((size_t)bp << 12) + l] = acc;
  const float m = wave_max_f(acc);
  if (lane == 0) red[wid] = m;
  __syncthreads();
  if (t == 0) bmax[bp * 16 + lc] = fmaxf(fmaxf(red[0], red[1]), fmaxf(red[2], red[3]));
}

// ---------------- global softmax stats ----------------
__global__ __launch_bounds__(256)
void gsm_kernel(const float* __restrict__ dg, const float* __restrict__ bmax,
                float* __restrict__ mrow, float* __restrict__ srow){
  __shared__ float red[4];
  const int bp = blockIdx.x, t = threadIdx.x, lane = t & 63, wid = t >> 6;
  float m = -INFINITY;
  #pragma unroll
  for (int i = 0; i < 16; ++i) m = fmaxf(m, bmax[bp * 16 + i]);
  float s = 0.f;
  #pragma unroll
  for (int i = 0; i < 16; ++i) s += expf(dg[((size_t)bp << 12) + (i << 8) + t] - m);
  s = wave_sum_f(s);
  if (lane == 0) red[wid] = s;
  __syncthreads();
  if (t == 0){
    mrow[bp] = m;
    srow[bp] = 1.f / (red[0] + red[1] + red[2] + red[3]);
  }
}

// ---------------- PV: grid (b,p) x 8 channel-groups -----------------------
__global__ __launch_bounds__(256)
void pv_kernel(const float* __restrict__ feat3, const float* __restrict__ dg,
               const float* __restrict__ mrow, const float* __restrict__ srow,
               float* __restrict__ outraw){
  __shared__ float p_sh[HW3];
  const int blk = blockIdx.x;       // 1024
  const int bp = blk >> 3, cg = blk & 7;
  const int b = bp >> 6;
  const int t = threadIdx.x, lane = t & 63, wid = t >> 6;
  const float* fb = feat3 + ((size_t)b << 20);
  const float m = mrow[bp], inv = srow[bp];
  #pragma unroll
  for (int i = 0; i < 16; ++i){
    const int l = (i << 8) + t;
    p_sh[l] = expf(dg[((size_t)bp << 12) + l] - m) * inv;
  }
  __syncthreads();
  const float4* pv4 = reinterpret_cast<const float4*>(p_sh);
  #pragma unroll
  for (int j = 0; j < 8; ++j){
    const int c = (cg << 5) + (wid << 3) + j;
    const float4* rv = reinterpret_cast<const float4*>(fb + ((size_t)c << 12));
    float s = 0.f;
    #pragma unroll
    for (int i = 0; i < 16; ++i){
      const float4 a = rv[(i << 6) + lane];
      const float4 pp = pv4[(i << 6) + lane];
      s += a.x * pp.x + a.y * pp.y + a.z * pp.z + a.w * pp.w;
    }
    s = wave_sum_f(s);
    if (lane == 0) outraw[bp * C3 + c] = s;
  }
}

// ---------------- normalize rows of 256 ----------------
__global__ __launch_bounds__(256)
void norm_kernel(const float* __restrict__ outraw, float* __restrict__ out3){
  __shared__ float red[4];
  const int bp = blockIdx.x, t = threadIdx.x, lane = t & 63, wid = t >> 6;
  const float v = outraw[bp * C3 + t];
  const float sq = wave_sum_f(v * v);
  if (lane == 0) red[wid] = sq;
  __syncthreads();
  const float nrm = fmaxf(sqrtf(red[0] + red[1] + red[2] + red[3]), 1e-7f);
  out3[(size_t)bp * C3 + t] = v / nrm;
}

// ---------------- launch ----------------
extern "C" void kernel_launch(void* const* d_in, const int* in_sizes, int n_in,
                              void* d_out, int out_size, void* d_ws, size_t ws_size,
                              hipStream_t stream){
  const float* feat0 = (const float*)d_in[0];
  const float* feat1 = (const float*)d_in[1];
  const float* feat2 = (const float*)d_in[2];
  const float* feat3 = (const float*)d_in[3];
  const int*   pid0  = (const int*)d_in[4];
  const int*   pid1  = (const int*)d_in[5];
  const int*   pid2  = (const int*)d_in[6];

  float* out  = (float*)d_out;
  float* out0 = out;                 // 128*64
  float* out1 = out + 8192;          // 128*128
  float* out2 = out + 24576;         // 128*256
  float* out3 = out + 57344;         // 128*256

  float* ws       = (float*)d_ws;
  float* ent_ws   = ws;                         // 8192
  int*   idx_ws   = (int*)(ws + 8192);          // 128
  float* dotsl_ws = ws + 8320;                  // 2*49*4096 = 401408
  float* dg_ws    = dotsl_ws + 401408;          // 128*4096  = 524288
  float* bmax_ws  = dg_ws + 524288;             // 128*16
  float* mrow_ws  = bmax_ws + 2048;             // 128
  float* srow_ws  = mrow_ws + 128;              // 128
  float* oraw_ws  = srow_ws + 128;              // 128*256

  sample_kernel<64, 16><<<128, 64, 0, stream>>>(feat0, pid0, out0);
  sample_kernel<128, 14><<<128, 64, 0, stream>>>(feat1, pid1, out1);
  sample_kernel<256, 12><<<128, 64, 0, stream>>>(feat2, pid2, out2);

  ldots_kernel<<<1664, 256, 0, stream>>>(feat3, dotsl_ws);
  lent_kernel<<<32, 256, 0, stream>>>(dotsl_ws, ent_ws);
  select_kernel<<<2, 1024, 0, stream>>>(ent_ws, idx_ws);
  gdots_kernel<<<2048, 256, 0, stream>>>(feat3, idx_ws, dg_ws, bmax_ws);
  gsm_kernel<<<128, 256, 0, stream>>>(dg_ws, bmax_ws, mrow_ws, srow_ws);
  pv_kernel<<<1024, 256, 0, stream>>>(feat3, dg_ws, mrow_ws, srow_ws, oraw_ws);
  norm_kernel<<<128, 256, 0, stream>>>(oraw_ws, out3);
}

// Round 3
// 160.657 us; speedup vs baseline: 9.2204x; 1.7330x over previous
//
#include <hip/hip_runtime.h>
#include <hip/hip_bf16.h>
#include <cstdint>
#include <cstddef>

// ---------------- wave helpers (wave64) ----------------
__device__ __forceinline__ float wave_max_f(float v){
  #pragma unroll
  for (int m = 32; m; m >>= 1) v = fmaxf(v, __shfl_xor(v, m));
  return v;
}
__device__ __forceinline__ float wave_sum_f(float v){
  #pragma unroll
  for (int m = 32; m; m >>= 1) v += __shfl_xor(v, m);
  return v;
}
__device__ __forceinline__ int wave_sum_i(int v){
  #pragma unroll
  for (int m = 32; m; m >>= 1) v += __shfl_xor(v, m);
  return v;
}

// ---------------- _sample_early: gather + normalize ----------------
template<int C, int LOGHW>
__global__ __launch_bounds__(64)
void sample_kernel(const float* __restrict__ feat, const int* __restrict__ pid,
                   float* __restrict__ out){
  const int r = blockIdx.x;          // 0..127
  const int b = r >> 6, p = r & 63;
  const int lane = threadIdx.x;      // 0..63
  const int l = pid[p];
  const float* fb = feat + (((size_t)b * C) << LOGHW);
  constexpr int V = C / 64;
  float v[V];
  float sq = 0.f;
  #pragma unroll
  for (int i = 0; i < V; ++i){
    const int c = lane + 64 * i;
    v[i] = fb[(((size_t)c) << LOGHW) + l];
    sq += v[i] * v[i];
  }
  sq = wave_sum_f(sq);
  const float nrm = fmaxf(sqrtf(sq), 1e-7f);
  #pragma unroll
  for (int i = 0; i < V; ++i)
    out[(size_t)r * C + lane + 64 * i] = v[i] / nrm;
}

// ---------------- qs_attn constants ----------------
#define C3   256
#define HW3  4096
#define NP   64

// ---------------- local dots (scrambled faithful mapping) ----------------
__global__ __launch_bounds__(256)
void ldots_kernel(const float* __restrict__ feat3, float* __restrict__ dotsl){
  const int blk = blockIdx.x;
  const int kg = blk % 13;
  const int bh = blk / 13;
  const int b = bh >> 6, h = bh & 63;
  const int tid = threadIdx.x, wid = tid >> 6, lane = tid & 63;
  const int k2 = kg * 4 + wid;
  if (k2 >= 49) return;
  const float* fb = feat3 + ((size_t)b << 20);
  const int w = lane;
  const int f0 = k2 << 8;
  int c  = f0 / 49;
  int k  = f0 % 49;
  int ki = k / 7, kj = k % 7;
  float acc = 0.f;
  for (int c2 = 0; c2 < 256; ++c2){
    const int hh = h + ki - 3;
    const int ww = w + kj - 3;
    float wv = 0.f;
    if ((unsigned)hh < 64u && (unsigned)ww < 64u)
      wv = fb[((size_t)c << 12) + (hh << 6) + ww];
    acc += wv * fb[((size_t)c2 << 12) + (h << 6) + w];
    ++kj;
    if (kj == 7){ kj = 0; ++ki; if (ki == 7){ ki = 0; ++c; } }
  }
  dotsl[(((size_t)(b * 49 + k2)) << 12) + (h << 6) + w] = acc;
}

// ---------------- local entropy (softmax over 49, k-major layout) ----------
__global__ __launch_bounds__(256)
void lent_kernel(const float* __restrict__ dotsl, float* __restrict__ ent){
  const int blk = blockIdx.x;       // 32
  const int b = blk >> 4;
  const int l = ((blk & 15) << 8) + threadIdx.x;
  const float* dl = dotsl + (((size_t)b * 49) << 12);
  float m = -INFINITY;
  #pragma unroll
  for (int k = 0; k < 49; ++k) m = fmaxf(m, dl[((size_t)k << 12) + l]);
  float s = 0.f, ts = 0.f;
  #pragma unroll
  for (int k = 0; k < 49; ++k){
    const float d = dl[((size_t)k << 12) + l] - m;
    const float e = expf(d);
    s += e; ts += e * d;
  }
  ent[b * HW3 + l] = logf(s) - ts / s;
}

// ---------------- rank-based top-64 selection (stable, exact) -------------
// key(i) = (monotonic_u32(ent[i]) << 32) | i  -- strict total order matching
// stable argsort. rank(i) = #{j : key(j) < key(i)}; rank<64 -> winner.
// grid = 2 batches x 64 blocks ; block 256 (4 waves x 16 candidates each).
__global__ __launch_bounds__(256)
void rank_select_kernel(const float* __restrict__ ent, int* __restrict__ idx){
  __shared__ unsigned long long keys[HW3];   // 32 KB
  const int blk = blockIdx.x;
  const int b  = blk >> 6;
  const int cg = blk & 63;                   // 64 candidates per block
  const int t = threadIdx.x, wid = t >> 6, lane = t & 63;
  for (int i = t; i < HW3; i += 256){
    const float e = ent[b * HW3 + i];
    unsigned u = __float_as_uint(e);
    u = (u & 0x80000000u) ? ~u : (u | 0x80000000u);
    keys[i] = ((unsigned long long)u << 32) | (unsigned)i;
  }
  __syncthreads();
  #pragma unroll
  for (int j = 0; j < 16; ++j){
    const int cand = (cg << 6) + (wid << 4) + j;
    const unsigned long long kc = keys[cand];
    int cnt = 0;
    #pragma unroll 8
    for (int i = lane; i < HW3; i += 64)
      cnt += (keys[i] < kc) ? 1 : 0;
    cnt = wave_sum_i(cnt);
    if (lane == 0 && cnt < NP) idx[b * NP + cnt] = cand;
  }
}

// ---------------- global dots: grid (b,p) x 16 l-chunks -------------------
__global__ __launch_bounds__(256)
void gdots_kernel(const float* __restrict__ feat3, const int* __restrict__ idx,
                  float* __restrict__ dg, float* __restrict__ bmax){
  __shared__ float q_sh[C3];
  __shared__ float red[4];
  const int blk = blockIdx.x;       // 2048
  const int bp = blk >> 4, lc = blk & 15;
  const int b = bp >> 6;
  const int t = threadIdx.x, lane = t & 63, wid = t >> 6;
  const float* fb = feat3 + ((size_t)b << 20);
  const int pidx = idx[bp];
  q_sh[t] = fb[((size_t)t << 12) + pidx];
  __syncthreads();
  const int l = (lc << 8) + t;
  float acc = 0.f;
  #pragma unroll 8
  for (int c = 0; c < C3; ++c) acc += fb[((size_t)c << 12) + l] * q_sh[c];
  dg[((size_t)bp << 12) + l] = acc;
  const float m = wave_max_f(acc);
  if (lane == 0) red[wid] = m;
  __syncthreads();
  if (t == 0) bmax[bp * 16 + lc] = fmaxf(fmaxf(red[0], red[1]), fmaxf(red[2], red[3]));
}

// ---------------- global softmax stats ----------------
__global__ __launch_bounds__(256)
void gsm_kernel(const float* __restrict__ dg, const float* __restrict__ bmax,
                float* __restrict__ mrow, float* __restrict__ srow){
  __shared__ float red[4];
  const int bp = blockIdx.x, t = threadIdx.x, lane = t & 63, wid = t >> 6;
  float m = -INFINITY;
  #pragma unroll
  for (int i = 0; i < 16; ++i) m = fmaxf(m, bmax[bp * 16 + i]);
  float s = 0.f;
  #pragma unroll
  for (int i = 0; i < 16; ++i) s += expf(dg[((size_t)bp << 12) + (i << 8) + t] - m);
  s = wave_sum_f(s);
  if (lane == 0) red[wid] = s;
  __syncthreads();
  if (t == 0){
    mrow[bp] = m;
    srow[bp] = 1.f / (red[0] + red[1] + red[2] + red[3]);
  }
}

// ---------------- PV: grid (b,p) x 8 channel-groups -----------------------
__global__ __launch_bounds__(256)
void pv_kernel(const float* __restrict__ feat3, const float* __restrict__ dg,
               const float* __restrict__ mrow, const float* __restrict__ srow,
               float* __restrict__ outraw){
  __shared__ float p_sh[HW3];
  const int blk = blockIdx.x;       // 1024
  const int bp = blk >> 3, cg = blk & 7;
  const int b = bp >> 6;
  const int t = threadIdx.x, lane = t & 63, wid = t >> 6;
  const float* fb = feat3 + ((size_t)b << 20);
  const float m = mrow[bp], inv = srow[bp];
  #pragma unroll
  for (int i = 0; i < 16; ++i){
    const int l = (i << 8) + t;
    p_sh[l] = expf(dg[((size_t)bp << 12) + l] - m) * inv;
  }
  __syncthreads();
  const float4* pv4 = reinterpret_cast<const float4*>(p_sh);
  #pragma unroll
  for (int j = 0; j < 8; ++j){
    const int c = (cg << 5) + (wid << 3) + j;
    const float4* rv = reinterpret_cast<const float4*>(fb + ((size_t)c << 12));
    float s = 0.f;
    #pragma unroll
    for (int i = 0; i < 16; ++i){
      const float4 a = rv[(i << 6) + lane];
      const float4 pp = pv4[(i << 6) + lane];
      s += a.x * pp.x + a.y * pp.y + a.z * pp.z + a.w * pp.w;
    }
    s = wave_sum_f(s);
    if (lane == 0) outraw[bp * C3 + c] = s;
  }
}

// ---------------- normalize rows of 256 ----------------
__global__ __launch_bounds__(256)
void norm_kernel(const float* __restrict__ outraw, float* __restrict__ out3){
  __shared__ float red[4];
  const int bp = blockIdx.x, t = threadIdx.x, lane = t & 63, wid = t >> 6;
  const float v = outraw[bp * C3 + t];
  const float sq = wave_sum_f(v * v);
  if (lane == 0) red[wid] = sq;
  __syncthreads();
  const float nrm = fmaxf(sqrtf(red[0] + red[1] + red[2] + red[3]), 1e-7f);
  out3[(size_t)bp * C3 + t] = v / nrm;
}

// ---------------- launch ----------------
extern "C" void kernel_launch(void* const* d_in, const int* in_sizes, int n_in,
                              void* d_out, int out_size, void* d_ws, size_t ws_size,
                              hipStream_t stream){
  const float* feat0 = (const float*)d_in[0];
  const float* feat1 = (const float*)d_in[1];
  const float* feat2 = (const float*)d_in[2];
  const float* feat3 = (const float*)d_in[3];
  const int*   pid0  = (const int*)d_in[4];
  const int*   pid1  = (const int*)d_in[5];
  const int*   pid2  = (const int*)d_in[6];

  float* out  = (float*)d_out;
  float* out0 = out;                 // 128*64
  float* out1 = out + 8192;          // 128*128
  float* out2 = out + 24576;         // 128*256
  float* out3 = out + 57344;         // 128*256

  float* ws       = (float*)d_ws;
  float* ent_ws   = ws;                         // 8192
  int*   idx_ws   = (int*)(ws + 8192);          // 128
  float* dotsl_ws = ws + 8320;                  // 2*49*4096 = 401408
  float* dg_ws    = dotsl_ws + 401408;          // 128*4096  = 524288
  float* bmax_ws  = dg_ws + 524288;             // 128*16
  float* mrow_ws  = bmax_ws + 2048;             // 128
  float* srow_ws  = mrow_ws + 128;              // 128
  float* oraw_ws  = srow_ws + 128;              // 128*256

  sample_kernel<64, 16><<<128, 64, 0, stream>>>(feat0, pid0, out0);
  sample_kernel<128, 14><<<128, 64, 0, stream>>>(feat1, pid1, out1);
  sample_kernel<256, 12><<<128, 64, 0, stream>>>(feat2, pid2, out2);

  ldots_kernel<<<1664, 256, 0, stream>>>(feat3, dotsl_ws);
  lent_kernel<<<32, 256, 0, stream>>>(dotsl_ws, ent_ws);
  rank_select_kernel<<<128, 256, 0, stream>>>(ent_ws, idx_ws);
  gdots_kernel<<<2048, 256, 0, stream>>>(feat3, idx_ws, dg_ws, bmax_ws);
  gsm_kernel<<<128, 256, 0, stream>>>(dg_ws, bmax_ws, mrow_ws, srow_ws);
  pv_kernel<<<1024, 256, 0, stream>>>(feat3, dg_ws, mrow_ws, srow_ws, oraw_ws);
  norm_kernel<<<128, 256, 0, stream>>>(oraw_ws, out3);
}